// Round 1
// baseline (1021.870 us; speedup 1.0000x reference)
//
#include <hip/hip_runtime.h>

typedef unsigned short u16;
typedef __attribute__((ext_vector_type(4))) float floatx4;
typedef __attribute__((ext_vector_type(8))) _Float16 half8;
typedef __attribute__((ext_vector_type(8))) unsigned short ushort8v;

__device__ __forceinline__ u16 f2h(float f) {
  union { _Float16 h; u16 u; } v; v.h = (_Float16)f; return v.u;
}

__device__ __forceinline__ void async_ld16(const void* g, void* l) {
  __builtin_amdgcn_global_load_lds(
      (const __attribute__((address_space(1))) void*)g,
      (__attribute__((address_space(3))) void*)l, 16, 0, 0);
}

// ---------------- W transpose: src fp32 [K][N] -> dst fp16 [N][K] ----------------
__global__ __launch_bounds__(256)
void wtrans_kernel(const float* __restrict__ src, u16* __restrict__ dst, int K, int N) {
  __shared__ float tile[32][33];
  int t = threadIdx.x;
  int n0 = blockIdx.x * 32, k0 = blockIdx.y * 32;
  int tx = t & 31, ty = t >> 5;  // ty 0..7
#pragma unroll
  for (int i = 0; i < 4; ++i) {
    int k = ty + i * 8;
    tile[k][tx] = src[(size_t)(k0 + k) * N + n0 + tx];
  }
  __syncthreads();
#pragma unroll
  for (int i = 0; i < 4; ++i) {
    int n = ty + i * 8;
    dst[(size_t)(n0 + n) * K + k0 + tx] = f2h(tile[tx][n]);
  }
}

// ---------------- LayerNorm: x fp32 [8192][1024] -> h fp16 ----------------
__global__ __launch_bounds__(256)
void ln_kernel(const float* __restrict__ x, const float* __restrict__ g,
               const float* __restrict__ bb, u16* __restrict__ h) {
  int r = blockIdx.x, t = threadIdx.x;
  int lane = t & 63, wave = t >> 6;
  const float* xr = x + (size_t)r * 1024;
  float4 xv = *(const float4*)(xr + t * 4);
  __shared__ float red[8];
  float s = xv.x + xv.y + xv.z + xv.w;
#pragma unroll
  for (int o = 32; o; o >>= 1) s += __shfl_down(s, o, 64);
  if (lane == 0) red[wave] = s;
  __syncthreads();
  float mu = (red[0] + red[1] + red[2] + red[3]) * (1.0f / 1024.0f);
  float dx = xv.x - mu, dy = xv.y - mu, dz = xv.z - mu, dw = xv.w - mu;
  float s2 = dx * dx + dy * dy + dz * dz + dw * dw;
#pragma unroll
  for (int o = 32; o; o >>= 1) s2 += __shfl_down(s2, o, 64);
  if (lane == 0) red[4 + wave] = s2;
  __syncthreads();
  float var = (red[4] + red[5] + red[6] + red[7]) * (1.0f / 1024.0f);
  float rs = rsqrtf(var + 1e-5f);
  float4 gv = *(const float4*)(g + t * 4);
  float4 bv = *(const float4*)(bb + t * 4);
  ushort4 o4;
  o4.x = f2h(dx * rs * gv.x + bv.x);
  o4.y = f2h(dy * rs * gv.y + bv.y);
  o4.z = f2h(dz * rs * gv.z + bv.z);
  o4.w = f2h(dw * rs * gv.w + bv.w);
  *(ushort4*)(h + (size_t)r * 1024 + t * 4) = o4;
}

// ---------------- GEMM: C[M,N] = A_fp16[M,K] @ BT_fp16[N,K] + bias (+resid) ----------------
// EPI 0: fp16 out.  EPI 1: fp32 out + residual.
template <int EPI>
__global__ __launch_bounds__(256, 2)
void gemm_bt(const u16* __restrict__ A, const u16* __restrict__ BT,
             const float* __restrict__ bias, const float* __restrict__ resid,
             u16* __restrict__ outh, float* __restrict__ outf,
             int M, int N, int K) {
  __shared__ u16 As[128 * 32];
  __shared__ u16 Bs[128 * 32];
  int t = threadIdx.x, lane = t & 63, wave = t >> 6;
  int m0 = blockIdx.y * 128, n0 = blockIdx.x * 128;
  int wm = (wave >> 1) * 64, wn = (wave & 1) * 64;
  floatx4 acc[4][4];
#pragma unroll
  for (int i = 0; i < 4; ++i)
#pragma unroll
    for (int j = 0; j < 4; ++j) acc[i][j] = (floatx4){0.f, 0.f, 0.f, 0.f};
  const u16* Ag = A + (size_t)(m0 + (t >> 2)) * K + (t & 3) * 8;
  const u16* Bg = BT + (size_t)(n0 + (t >> 2)) * K + (t & 3) * 8;
  u16* Asp = As + t * 8;
  u16* Bsp = Bs + t * 8;
  int qrow = lane & 15, qk = (lane >> 4) * 8;
  for (int k0 = 0; k0 < K; k0 += 32) {
    __syncthreads();
    async_ld16(Ag + k0, Asp);
    async_ld16(Ag + k0 + (size_t)64 * K, Asp + 64 * 32);
    async_ld16(Bg + k0, Bsp);
    async_ld16(Bg + k0 + (size_t)64 * K, Bsp + 64 * 32);
    __syncthreads();
    half8 af[4], bf[4];
#pragma unroll
    for (int i = 0; i < 4; ++i)
      af[i] = *(const half8*)(As + (wm + i * 16 + qrow) * 32 + qk);
#pragma unroll
    for (int j = 0; j < 4; ++j)
      bf[j] = *(const half8*)(Bs + (wn + j * 16 + qrow) * 32 + qk);
#pragma unroll
    for (int i = 0; i < 4; ++i)
#pragma unroll
      for (int j = 0; j < 4; ++j)
        acc[i][j] = __builtin_amdgcn_mfma_f32_16x16x32_f16(af[i], bf[j], acc[i][j], 0, 0, 0);
  }
#pragma unroll
  for (int i = 0; i < 4; ++i)
#pragma unroll
    for (int j = 0; j < 4; ++j)
#pragma unroll
      for (int r = 0; r < 4; ++r) {
        int row = m0 + wm + i * 16 + (lane >> 4) * 4 + r;
        int col = n0 + wn + j * 16 + (lane & 15);
        float v = acc[i][j][r] + bias[col];
        size_t idx = (size_t)row * N + col;
        if (EPI == 0) {
          outh[idx] = f2h(v);
        } else {
          outf[idx] = v + resid[idx];
        }
      }
}

// ---------------- V transpose: qkv v-slice -> vT fp16 [bh][d][t] ----------------
__global__ __launch_bounds__(256)
void vtrans_kernel(const u16* __restrict__ qkv, u16* __restrict__ vT) {
  __shared__ u16 tile[64][80];  // [tk][d], padded to keep 16B align
  int t = threadIdx.x;
  int bh = blockIdx.x >> 4, chunk = blockIdx.x & 15;
  int b = bh >> 4, h = bh & 15;
#pragma unroll
  for (int it = 0; it < 2; ++it) {
    int row = it * 32 + (t >> 3), seg = t & 7;
    const u16* src = qkv + (size_t)(b * 1024 + chunk * 64 + row) * 3072 + 2048 + h * 64 + seg * 8;
    *(ushort8v*)&tile[row][seg * 8] = *(const ushort8v*)src;
  }
  __syncthreads();
#pragma unroll
  for (int it = 0; it < 2; ++it) {
    int d = it * 32 + (t >> 3), tks = t & 7;
    ushort8v v;
#pragma unroll
    for (int e = 0; e < 8; ++e) v[e] = tile[tks * 8 + e][d];
    *(ushort8v*)(vT + ((size_t)bh * 64 + d) * 1024 + chunk * 64 + tks * 8) = v;
  }
}

// ---------------- Attention: scores + softmax + attn store + PV ----------------
// grid: 8192 = 128 bh * 64 qtiles ; block 256 (4 waves); 16 q-rows per block
__global__ __launch_bounds__(256, 2)
void attn_kernel(const u16* __restrict__ qkv, const u16* __restrict__ vT,
                 float* __restrict__ attnO, u16* __restrict__ P) {
  const int SW = 1032;  // fp32 row stride (pad 8): 4128 B = 258*16, banks spread
  __shared__ float s_lds[16 * SW];
  __shared__ float inv16[16];
  int t = threadIdx.x, lane = t & 63, wave = t >> 6;
  int qt = blockIdx.x & 63, bh = blockIdx.x >> 6;
  int b = bh >> 4, h = bh & 15;
  int tq0 = qt * 16;
  int m = lane & 15, qe = lane >> 4;

  // phase 1: S = (Q Kt) * scale  into LDS
  const u16* qbase = qkv + (size_t)(b * 1024 + tq0 + m) * 3072 + h * 64 + qe * 8;
  half8 a0 = *(const half8*)(qbase);
  half8 a1 = *(const half8*)(qbase + 32);
#pragma unroll 4
  for (int ct = 0; ct < 16; ++ct) {
    int kt = wave * 256 + ct * 16;
    const u16* kbase = qkv + (size_t)(b * 1024 + kt + m) * 3072 + 1024 + h * 64 + qe * 8;
    half8 b0 = *(const half8*)(kbase);
    half8 b1 = *(const half8*)(kbase + 32);
    floatx4 acc = (floatx4){0.f, 0.f, 0.f, 0.f};
    acc = __builtin_amdgcn_mfma_f32_16x16x32_f16(a0, b0, acc, 0, 0, 0);
    acc = __builtin_amdgcn_mfma_f32_16x16x32_f16(a1, b1, acc, 0, 0, 0);
#pragma unroll
    for (int r = 0; r < 4; ++r)
      s_lds[(qe * 4 + r) * SW + kt + m] = acc[r] * 0.125f;
  }
  __syncthreads();

  // phase 2: exact softmax per row (16 threads/row)
  int row = t >> 4, sub = t & 15;
  float* srow = s_lds + row * SW;
  float mx = -1e30f;
#pragma unroll 8
  for (int i = 0; i < 64; ++i) mx = fmaxf(mx, srow[sub + 16 * i]);
#pragma unroll
  for (int o = 8; o; o >>= 1) mx = fmaxf(mx, __shfl_xor(mx, o, 16));
  float sum = 0.f;
#pragma unroll 8
  for (int i = 0; i < 64; ++i) {
    float e = __expf(srow[sub + 16 * i] - mx);
    srow[sub + 16 * i] = e;
    sum += e;
  }
#pragma unroll
  for (int o = 8; o; o >>= 1) sum += __shfl_xor(sum, o, 16);
  if (sub == 0) inv16[row] = 1.0f / sum;
  __syncthreads();

  // phase 3: normalized attn -> global (coalesced float2)
  float inv = inv16[row];
  float* arow = attnO + ((size_t)(bh * 1024 + tq0 + row)) * 1024;
#pragma unroll 4
  for (int i = 0; i < 32; ++i) {
    int col = 2 * sub + 32 * i;
    float2 v = make_float2(srow[col] * inv, srow[col + 1] * inv);
    *(float2*)(arow + col) = v;
  }

  // phase 4: O = P V  (unnormalized exp; scale rows by inv in epilogue)
  floatx4 oacc = (floatx4){0.f, 0.f, 0.f, 0.f};
  const u16* vbase = vT + ((size_t)bh * 64 + wave * 16 + m) * 1024 + qe * 8;
  const float* prow = s_lds + m * SW + qe * 8;
#pragma unroll 4
  for (int k0 = 0; k0 < 1024; k0 += 32) {
    float4 p0 = *(const float4*)(prow + k0);
    float4 p1 = *(const float4*)(prow + k0 + 4);
    half8 af;
    af[0] = (_Float16)p0.x; af[1] = (_Float16)p0.y;
    af[2] = (_Float16)p0.z; af[3] = (_Float16)p0.w;
    af[4] = (_Float16)p1.x; af[5] = (_Float16)p1.y;
    af[6] = (_Float16)p1.z; af[7] = (_Float16)p1.w;
    half8 bv = *(const half8*)(vbase + k0);
    oacc = __builtin_amdgcn_mfma_f32_16x16x32_f16(af, bv, oacc, 0, 0, 0);
  }
#pragma unroll
  for (int r = 0; r < 4; ++r) {
    int orow = qe * 4 + r;
    float v = oacc[r] * inv16[orow];
    P[(size_t)(b * 1024 + tq0 + orow) * 1024 + h * 64 + wave * 16 + m] = f2h(v);
  }
}

extern "C" void kernel_launch(void* const* d_in, const int* in_sizes, int n_in,
                              void* d_out, int out_size, void* d_ws, size_t ws_size,
                              hipStream_t stream) {
  const float* x     = (const float*)d_in[0];
  const float* ln_g  = (const float*)d_in[1];
  const float* ln_b  = (const float*)d_in[2];
  const float* W_qkv = (const float*)d_in[3];
  const float* b_qkv = (const float*)d_in[4];
  const float* W_fc  = (const float*)d_in[5];
  const float* b_fc  = (const float*)d_in[6];
  float* outp  = (float*)d_out;
  float* attnp = outp + (size_t)8 * 1024 * 1024;

  u16* ws    = (u16*)d_ws;
  u16* h     = ws;               // [8192,1024] fp16 (reused as P after QKV GEMM)
  u16* wqkvT = ws + 8388608;     // [3072,1024]
  u16* wfcT  = ws + 11534336;    // [1024,1024]
  u16* qkv   = ws + 12582912;    // [8192,3072]
  u16* vT    = ws + 37748736;    // [128,64,1024]
  u16* P     = h;

  wtrans_kernel<<<dim3(96, 32), 256, 0, stream>>>(W_qkv, wqkvT, 1024, 3072);
  wtrans_kernel<<<dim3(32, 32), 256, 0, stream>>>(W_fc, wfcT, 1024, 1024);
  ln_kernel<<<8192, 256, 0, stream>>>(x, ln_g, ln_b, h);
  gemm_bt<0><<<dim3(24, 64), 256, 0, stream>>>(h, wqkvT, b_qkv, nullptr, qkv, nullptr,
                                               8192, 3072, 1024);
  vtrans_kernel<<<2048, 256, 0, stream>>>(qkv, vT);
  attn_kernel<<<8192, 256, 0, stream>>>(qkv, vT, attnp, P);
  gemm_bt<1><<<dim3(8, 64), 256, 0, stream>>>(P, wfcT, b_fc, x, nullptr, outp,
                                              8192, 1024, 1024);
}

// Round 2
// 911.700 us; speedup vs baseline: 1.1208x; 1.1208x over previous
//
#include <hip/hip_runtime.h>

typedef unsigned short u16;
typedef __attribute__((ext_vector_type(4))) float floatx4;
typedef __attribute__((ext_vector_type(8))) _Float16 half8;
typedef __attribute__((ext_vector_type(8))) unsigned short ushort8v;

__device__ __forceinline__ u16 f2h(float f) {
  union { _Float16 h; u16 u; } v; v.h = (_Float16)f; return v.u;
}

__device__ __forceinline__ void async_ld16(const void* g, void* l) {
  __builtin_amdgcn_global_load_lds(
      (const __attribute__((address_space(1))) void*)g,
      (__attribute__((address_space(3))) void*)l, 16, 0, 0);
}

// ---------------- W transpose: src fp32 [K][N] -> dst fp16 [N][K] ----------------
__global__ __launch_bounds__(256)
void wtrans_kernel(const float* __restrict__ src, u16* __restrict__ dst, int K, int N) {
  __shared__ float tile[32][33];
  int t = threadIdx.x;
  int n0 = blockIdx.x * 32, k0 = blockIdx.y * 32;
  int tx = t & 31, ty = t >> 5;  // ty 0..7
#pragma unroll
  for (int i = 0; i < 4; ++i) {
    int k = ty + i * 8;
    tile[k][tx] = src[(size_t)(k0 + k) * N + n0 + tx];
  }
  __syncthreads();
#pragma unroll
  for (int i = 0; i < 4; ++i) {
    int n = ty + i * 8;
    dst[(size_t)(n0 + n) * K + k0 + tx] = f2h(tile[tx][n]);
  }
}

// ---------------- LayerNorm: x fp32 [8192][1024] -> h fp16 ----------------
__global__ __launch_bounds__(256)
void ln_kernel(const float* __restrict__ x, const float* __restrict__ g,
               const float* __restrict__ bb, u16* __restrict__ h) {
  int r = blockIdx.x, t = threadIdx.x;
  int lane = t & 63, wave = t >> 6;
  const float* xr = x + (size_t)r * 1024;
  float4 xv = *(const float4*)(xr + t * 4);
  __shared__ float red[8];
  float s = xv.x + xv.y + xv.z + xv.w;
#pragma unroll
  for (int o = 32; o; o >>= 1) s += __shfl_down(s, o, 64);
  if (lane == 0) red[wave] = s;
  __syncthreads();
  float mu = (red[0] + red[1] + red[2] + red[3]) * (1.0f / 1024.0f);
  float dx = xv.x - mu, dy = xv.y - mu, dz = xv.z - mu, dw = xv.w - mu;
  float s2 = dx * dx + dy * dy + dz * dz + dw * dw;
#pragma unroll
  for (int o = 32; o; o >>= 1) s2 += __shfl_down(s2, o, 64);
  if (lane == 0) red[4 + wave] = s2;
  __syncthreads();
  float var = (red[4] + red[5] + red[6] + red[7]) * (1.0f / 1024.0f);
  float rs = rsqrtf(var + 1e-5f);
  float4 gv = *(const float4*)(g + t * 4);
  float4 bv = *(const float4*)(bb + t * 4);
  ushort4 o4;
  o4.x = f2h(dx * rs * gv.x + bv.x);
  o4.y = f2h(dy * rs * gv.y + bv.y);
  o4.z = f2h(dz * rs * gv.z + bv.z);
  o4.w = f2h(dw * rs * gv.w + bv.w);
  *(ushort4*)(h + (size_t)r * 1024 + t * 4) = o4;
}

// ---------------- GEMM: C[M,N] = A_fp16[M,K] @ BT_fp16[N,K] + bias (+resid) ----------------
template <int EPI>
__global__ __launch_bounds__(256, 2)
void gemm_bt(const u16* __restrict__ A, const u16* __restrict__ BT,
             const float* __restrict__ bias, const float* __restrict__ resid,
             u16* __restrict__ outh, float* __restrict__ outf,
             int M, int N, int K) {
  __shared__ u16 As[128 * 32];
  __shared__ u16 Bs[128 * 32];
  int t = threadIdx.x, lane = t & 63, wave = t >> 6;
  int m0 = blockIdx.y * 128, n0 = blockIdx.x * 128;
  int wm = (wave >> 1) * 64, wn = (wave & 1) * 64;
  floatx4 acc[4][4];
#pragma unroll
  for (int i = 0; i < 4; ++i)
#pragma unroll
    for (int j = 0; j < 4; ++j) acc[i][j] = (floatx4){0.f, 0.f, 0.f, 0.f};
  const u16* Ag = A + (size_t)(m0 + (t >> 2)) * K + (t & 3) * 8;
  const u16* Bg = BT + (size_t)(n0 + (t >> 2)) * K + (t & 3) * 8;
  u16* Asp = As + t * 8;
  u16* Bsp = Bs + t * 8;
  int qrow = lane & 15, qk = (lane >> 4) * 8;
  for (int k0 = 0; k0 < K; k0 += 32) {
    __syncthreads();
    async_ld16(Ag + k0, Asp);
    async_ld16(Ag + k0 + (size_t)64 * K, Asp + 64 * 32);
    async_ld16(Bg + k0, Bsp);
    async_ld16(Bg + k0 + (size_t)64 * K, Bsp + 64 * 32);
    __syncthreads();
    half8 af[4], bf[4];
#pragma unroll
    for (int i = 0; i < 4; ++i)
      af[i] = *(const half8*)(As + (wm + i * 16 + qrow) * 32 + qk);
#pragma unroll
    for (int j = 0; j < 4; ++j)
      bf[j] = *(const half8*)(Bs + (wn + j * 16 + qrow) * 32 + qk);
#pragma unroll
    for (int i = 0; i < 4; ++i)
#pragma unroll
      for (int j = 0; j < 4; ++j)
        acc[i][j] = __builtin_amdgcn_mfma_f32_16x16x32_f16(af[i], bf[j], acc[i][j], 0, 0, 0);
  }
#pragma unroll
  for (int i = 0; i < 4; ++i)
#pragma unroll
    for (int j = 0; j < 4; ++j)
#pragma unroll
      for (int r = 0; r < 4; ++r) {
        int row = m0 + wm + i * 16 + (lane >> 4) * 4 + r;
        int col = n0 + wn + j * 16 + (lane & 15);
        float v = acc[i][j][r] + bias[col];
        size_t idx = (size_t)row * N + col;
        if (EPI == 0) {
          outh[idx] = f2h(v);
        } else {
          outf[idx] = v + resid[idx];
        }
      }
}

// ---------------- V transpose: qkv v-slice -> vT fp16 [bh][d][t] ----------------
__global__ __launch_bounds__(256)
void vtrans_kernel(const u16* __restrict__ qkv, u16* __restrict__ vT) {
  __shared__ u16 tile[64][80];
  int t = threadIdx.x;
  int bh = blockIdx.x >> 4, chunk = blockIdx.x & 15;
  int b = bh >> 4, h = bh & 15;
#pragma unroll
  for (int it = 0; it < 2; ++it) {
    int row = it * 32 + (t >> 3), seg = t & 7;
    const u16* src = qkv + (size_t)(b * 1024 + chunk * 64 + row) * 3072 + 2048 + h * 64 + seg * 8;
    *(ushort8v*)&tile[row][seg * 8] = *(const ushort8v*)src;
  }
  __syncthreads();
#pragma unroll
  for (int it = 0; it < 2; ++it) {
    int d = it * 32 + (t >> 3), tks = t & 7;
    ushort8v v;
#pragma unroll
    for (int e = 0; e < 8; ++e) v[e] = tile[tks * 8 + e][d];
    *(ushort8v*)(vT + ((size_t)bh * 64 + d) * 1024 + chunk * 64 + tks * 8) = v;
  }
}

// ---------------- Attention ----------------
// grid: 8192 = 128 bh * 64 qtiles ; block 256 (4 waves); 16 q-rows per block.
// Scores live in registers (16 x floatx4 per lane = this wave's 16q x 256k segment).
// P (unnormalized exp) goes to LDS as fp16 with row stride 1032 elements:
// 516 words % 32 = 4 -> b128 A-frag reads start at bank 4*(m+qe), (m+qe)%8
// uniform over 64 lanes -> conflict-free minimum.
__global__ __launch_bounds__(256, 4)
void attn_kernel(const u16* __restrict__ qkv, const u16* __restrict__ vT,
                 float* __restrict__ attnO, u16* __restrict__ P) {
  const int SP = 1032;  // fp16 elements per P row
  __shared__ u16 P_lds[16 * SP];   // 33,024 B
  __shared__ float redA[64];
  __shared__ float redB[64];
  __shared__ float inv16[16];
  int t = threadIdx.x, lane = t & 63, wave = t >> 6;
  int qt = blockIdx.x & 63, bh = blockIdx.x >> 6;
  int b = bh >> 4, h = bh & 15;
  int tq0 = qt * 16;
  int m = lane & 15, qe = lane >> 4;

  // phase 1: S = (Q Kt) * scale, registers only
  const u16* qbase = qkv + (size_t)(b * 1024 + tq0 + m) * 3072 + h * 64 + qe * 8;
  half8 a0 = *(const half8*)(qbase);
  half8 a1 = *(const half8*)(qbase + 32);
  floatx4 acc[16];
#pragma unroll
  for (int ct = 0; ct < 16; ++ct) {
    int kt = wave * 256 + ct * 16;
    const u16* kbase = qkv + (size_t)(b * 1024 + kt + m) * 3072 + 1024 + h * 64 + qe * 8;
    half8 b0 = *(const half8*)(kbase);
    half8 b1 = *(const half8*)(kbase + 32);
    floatx4 a = (floatx4){0.f, 0.f, 0.f, 0.f};
    a = __builtin_amdgcn_mfma_f32_16x16x32_f16(a0, b0, a, 0, 0, 0);
    a = __builtin_amdgcn_mfma_f32_16x16x32_f16(a1, b1, a, 0, 0, 0);
#pragma unroll
    for (int r = 0; r < 4; ++r) a[r] *= 0.125f;
    acc[ct] = a;
  }

  // phase 2a: row max (in-lane over ct, then across the 16 lanes of this qe group)
  float mx[4];
#pragma unroll
  for (int r = 0; r < 4; ++r) mx[r] = -1e30f;
#pragma unroll
  for (int ct = 0; ct < 16; ++ct)
#pragma unroll
    for (int r = 0; r < 4; ++r) mx[r] = fmaxf(mx[r], acc[ct][r]);
#pragma unroll
  for (int o = 8; o; o >>= 1)
#pragma unroll
    for (int r = 0; r < 4; ++r) mx[r] = fmaxf(mx[r], __shfl_xor(mx[r], o, 16));
  if (m == 0) {
#pragma unroll
    for (int r = 0; r < 4; ++r) redA[wave * 16 + qe * 4 + r] = mx[r];
  }
  __syncthreads();
  float gmax[4];
#pragma unroll
  for (int r = 0; r < 4; ++r) {
    float v0 = redA[qe * 4 + r], v1 = redA[16 + qe * 4 + r];
    float v2 = redA[32 + qe * 4 + r], v3 = redA[48 + qe * 4 + r];
    gmax[r] = fmaxf(fmaxf(v0, v1), fmaxf(v2, v3));
  }

  // phase 2b: exp (registers), accumulate row sums, spill P to LDS as fp16
  float sm[4] = {0.f, 0.f, 0.f, 0.f};
#pragma unroll
  for (int ct = 0; ct < 16; ++ct) {
#pragma unroll
    for (int r = 0; r < 4; ++r) {
      float e = __expf(acc[ct][r] - gmax[r]);
      acc[ct][r] = e;
      sm[r] += e;
      P_lds[(qe * 4 + r) * SP + wave * 256 + ct * 16 + m] = f2h(e);
    }
  }
#pragma unroll
  for (int o = 8; o; o >>= 1)
#pragma unroll
    for (int r = 0; r < 4; ++r) sm[r] += __shfl_xor(sm[r], o, 16);
  if (m == 0) {
#pragma unroll
    for (int r = 0; r < 4; ++r) redB[wave * 16 + qe * 4 + r] = sm[r];
  }
  __syncthreads();
  if (t < 16) {
    float s = redB[t] + redB[16 + t] + redB[32 + t] + redB[48 + t];
    inv16[t] = 1.0f / s;
  }
  __syncthreads();

  // phase 3: normalized attn -> global, straight from registers
  float invr[4];
#pragma unroll
  for (int r = 0; r < 4; ++r) invr[r] = inv16[qe * 4 + r];
  float* abase = attnO + ((size_t)(bh * 1024 + tq0 + qe * 4)) * 1024 + wave * 256 + m;
#pragma unroll
  for (int r = 0; r < 4; ++r) {
    float* arow = abase + (size_t)r * 1024;
#pragma unroll
    for (int ct = 0; ct < 16; ++ct) arow[ct * 16] = acc[ct][r] * invr[r];
  }

  // phase 4: O = P V (fp16 P from LDS, conflict-free b128 reads)
  floatx4 oacc = (floatx4){0.f, 0.f, 0.f, 0.f};
  const u16* vbase = vT + ((size_t)bh * 64 + wave * 16 + m) * 1024 + qe * 8;
  const u16* prow = P_lds + m * SP + qe * 8;
#pragma unroll 8
  for (int k0 = 0; k0 < 1024; k0 += 32) {
    half8 af = *(const half8*)(prow + k0);
    half8 bv = *(const half8*)(vbase + k0);
    oacc = __builtin_amdgcn_mfma_f32_16x16x32_f16(af, bv, oacc, 0, 0, 0);
  }
#pragma unroll
  for (int r = 0; r < 4; ++r) {
    int orow = qe * 4 + r;
    float v = oacc[r] * invr[r];
    P[(size_t)(b * 1024 + tq0 + orow) * 1024 + h * 64 + wave * 16 + m] = f2h(v);
  }
}

extern "C" void kernel_launch(void* const* d_in, const int* in_sizes, int n_in,
                              void* d_out, int out_size, void* d_ws, size_t ws_size,
                              hipStream_t stream) {
  const float* x     = (const float*)d_in[0];
  const float* ln_g  = (const float*)d_in[1];
  const float* ln_b  = (const float*)d_in[2];
  const float* W_qkv = (const float*)d_in[3];
  const float* b_qkv = (const float*)d_in[4];
  const float* W_fc  = (const float*)d_in[5];
  const float* b_fc  = (const float*)d_in[6];
  float* outp  = (float*)d_out;
  float* attnp = outp + (size_t)8 * 1024 * 1024;

  u16* ws    = (u16*)d_ws;
  u16* h     = ws;               // [8192,1024] fp16 (reused as P after QKV GEMM)
  u16* wqkvT = ws + 8388608;     // [3072,1024]
  u16* wfcT  = ws + 11534336;    // [1024,1024]
  u16* qkv   = ws + 12582912;    // [8192,3072]
  u16* vT    = ws + 37748736;    // [128,64,1024]
  u16* P     = h;

  wtrans_kernel<<<dim3(96, 32), 256, 0, stream>>>(W_qkv, wqkvT, 1024, 3072);
  wtrans_kernel<<<dim3(32, 32), 256, 0, stream>>>(W_fc, wfcT, 1024, 1024);
  ln_kernel<<<8192, 256, 0, stream>>>(x, ln_g, ln_b, h);
  gemm_bt<0><<<dim3(24, 64), 256, 0, stream>>>(h, wqkvT, b_qkv, nullptr, qkv, nullptr,
                                               8192, 3072, 1024);
  vtrans_kernel<<<2048, 256, 0, stream>>>(qkv, vT);
  attn_kernel<<<8192, 256, 0, stream>>>(qkv, vT, attnp, P);
  gemm_bt<1><<<dim3(8, 64), 256, 0, stream>>>(P, wfcT, b_fc, x, nullptr, outp,
                                              8192, 1024, 1024);
}